// Round 9
// baseline (695.406 us; speedup 1.0000x reference)
//
#include <hip/hip_runtime.h>
#include <hip/hip_bf16.h>
#include <math.h>

#define DIM 1024
#define NB  4096      // B
#define N2  8192      // 2B
#define BT  256       // output tile dim
#define NT2 32        // N2 / BT
#define NTILES 528    // NT2*(NT2+1)/2 upper-triangular tiles

typedef float f32x4 __attribute__((ext_vector_type(4)));
typedef long  i64x2 __attribute__((ext_vector_type(2)));

__device__ __forceinline__ void gload_lds16(const unsigned char* g, unsigned char* l) {
    __builtin_amdgcn_global_load_lds((__attribute__((address_space(1))) void*)(g),
                                     (__attribute__((address_space(3))) void*)(l),
                                     16, 0, 0);
}

// fp8 e4m3fn encode, round-to-nearest-even (manual fallback)
__device__ __forceinline__ unsigned char to_fp8(float x) {
    unsigned int u = __float_as_uint(x);
    unsigned char s = (unsigned char)((u >> 24) & 0x80);
    int e = (int)((u >> 23) & 0xFF) - 127;
    unsigned int m = u & 0x7FFFFF;
    if (e >= -6) {
        if (e > 8) return s | 0x7E;
        unsigned int keep = m >> 20;
        unsigned int rest = m & 0xFFFFF;
        if (rest > 0x80000u || (rest == 0x80000u && (keep & 1))) keep++;
        unsigned int v = ((unsigned int)(e + 7) << 3) + keep;
        if (v >= 0x7F) v = 0x7E;
        return s | (unsigned char)v;
    }
    if (e < -10) return s;
    int drop = 14 - e;
    unsigned int sig = 0x800000u | m;
    unsigned int keep = sig >> drop;
    unsigned int rem  = sig & ((1u << drop) - 1u);
    unsigned int half = 1u << (drop - 1);
    if (rem > half || (rem == half && (keep & 1))) keep++;
    return s | (unsigned char)keep;
}

__device__ __forceinline__ unsigned int pk4_fp8(float a, float b, float c, float d) {
#if __has_builtin(__builtin_amdgcn_cvt_pk_fp8_f32)
    unsigned int q = 0;
    q = (unsigned int)__builtin_amdgcn_cvt_pk_fp8_f32(a, b, (int)q, false);
    q = (unsigned int)__builtin_amdgcn_cvt_pk_fp8_f32(c, d, (int)q, true);
    return q;
#else
    union { unsigned int u; unsigned char cc[4]; } q;
    q.cc[0] = to_fp8(a); q.cc[1] = to_fp8(b); q.cc[2] = to_fp8(c); q.cc[3] = to_fp8(d);
    return q.u;
#endif
}

// ---------------- Kernel 1: normalize rows, emit fp8 z (k-interleaved), pos --
// Column permutation within each 64-block: global col j -> stored byte
//   j<32: (j>>3)*16 + (j&7);  j>=32: ((j-32)>>3)*16 + 8 + ((j-32)&7)
// so one 16B granule g of a row holds k in {8g..8g+7} U {32+8g..32+8g+7}:
// ds_read_b128 yields BOTH K=32 MFMA slices. Same perm on A and B => cancels.
__global__ __launch_bounds__(256) void norm_kernel(
    const float* __restrict__ p1, const float* __restrict__ p2,
    unsigned char* __restrict__ zq, float* __restrict__ pos)
{
    const int r = blockIdx.x;
    const int t = threadIdx.x;
    const float4 x1 = ((const float4*)(p1 + (size_t)r * DIM))[t];
    const float4 x2 = ((const float4*)(p2 + (size_t)r * DIM))[t];
    float s1  = x1.x*x1.x + x1.y*x1.y + x1.z*x1.z + x1.w*x1.w;
    float s2  = x2.x*x2.x + x2.y*x2.y + x2.z*x2.z + x2.w*x2.w;
    float s12 = x1.x*x2.x + x1.y*x2.y + x1.z*x2.z + x1.w*x2.w;
#pragma unroll
    for (int off = 1; off < 64; off <<= 1) {
        s1  += __shfl_xor(s1,  off);
        s2  += __shfl_xor(s2,  off);
        s12 += __shfl_xor(s12, off);
    }
    __shared__ float ls[3][4];
    const int wid = t >> 6;
    if ((t & 63) == 0) { ls[0][wid] = s1; ls[1][wid] = s2; ls[2][wid] = s12; }
    __syncthreads();
    s1  = ls[0][0] + ls[0][1] + ls[0][2] + ls[0][3];
    s2  = ls[1][0] + ls[1][1] + ls[1][2] + ls[1][3];
    s12 = ls[2][0] + ls[2][1] + ls[2][2] + ls[2][3];
    const float rn1 = 1.0f / fmaxf(sqrtf(s1), 1e-12f);
    const float rn2 = 1.0f / fmaxf(sqrtf(s2), 1e-12f);
    if (t == 0) pos[r] = s12 * rn1 * rn2;

    const int j0 = (t << 2) & 63;       // col within 64-block
    const int kb = t >> 4;              // 64-block index
    const int pb = (j0 < 32) ? (((j0 >> 3) << 4) + (j0 & 7))
                             : ((((j0 - 32) >> 3) << 4) + 8 + ((j0 - 32) & 7));
    const size_t off8 = (size_t)kb * 64 + pb;
    *(unsigned int*)(zq + (size_t)r * DIM + off8) =
        pk4_fp8(x1.x * rn1, x1.y * rn1, x1.z * rn1, x1.w * rn1);
    *(unsigned int*)(zq + (size_t)(NB + r) * DIM + off8) =
        pk4_fp8(x2.x * rn2, x2.y * rn2, x2.z * rn2, x2.w * rn2);
}

// ------- Kernel 2: 256^2 fp8 symmetric z.z^T, 16 waves (4x4), 64x64/wave ----
// grid = 528 (one tile per block); 2 blocks co-resident per CU (LDS 64.5 KB,
// VGPR 64 -> 8 waves/SIMD) so one block's MFMA fills the other's barrier
// stalls, and the HW scheduler backfills the 16-extra-block tail onto
// first-freed CUs. One __syncthreads per K-tile.
__global__ __launch_bounds__(1024, 8) void sim_kernel(
    const unsigned char* __restrict__ zq,
    float* __restrict__ partials,    // [N2][NT2]
    float* __restrict__ lup)         // [NT2*NT2], rt<=ct slots only
{
    __shared__ __align__(16) unsigned char buf[2][2][BT * 64]; // 64 KB
    const int t    = threadIdx.x;
    const int lane = t & 63;
    const int wid  = t >> 6;       // 0..15
    const int wr   = wid >> 2;     // 0..3 (64-row strip)
    const int wc   = wid & 3;      // 0..3 (64-col strip)

    const int bid = blockIdx.x;
    const int job = (bid & 7) * (NTILES / 8) + (bid >> 3);   // bijective XCD swizzle
    int rt = 0;
    while ((rt + 1) * NT2 - (((rt + 1) * rt) >> 1) <= job) ++rt;
    const int ct = rt + job - (rt * NT2 - ((rt * (rt - 1)) >> 1));
    const bool isdiag = (rt == ct);
    const int row0 = rt * BT;
    const int col0 = ct * BT;

    const int fr = lane & 15;      // fragment row (A) / col (B)
    const int kg = lane >> 4;      // k-group 0..3
    const int aoff = (((wr << 6) + fr) << 6) + (kg << 4);
    const int boff = (((wc << 6) + fr) << 6) + (kg << 4);
    const unsigned char* Ab[2] = { &buf[0][0][0] + aoff, &buf[1][0][0] + aoff };
    const unsigned char* Bb[2] = { &buf[0][1][0] + boff, &buf[1][1][0] + boff };

    // staging: wave w covers rows [16w,16w+16); lane: row 16w+(l>>2), granule l&3
    const int srow = (wid << 4) + (lane >> 2);
    const int sgr  = (lane & 3) << 4;
    const unsigned char* arow = zq + (size_t)(row0 + srow) * DIM + sgr;
    const unsigned char* bcol = zq + (size_t)(col0 + srow) * DIM + sgr;

    f32x4 acc[4][4] = {};

    // prologue: K-tile 0 -> buf0
    gload_lds16(arow, &buf[0][0][wid << 10]);
    gload_lds16(bcol, &buf[0][1][wid << 10]);
    __syncthreads();

#pragma unroll
    for (int kt = 0; kt < 16; ++kt) {
        const int cur = kt & 1;
        if (kt < 15) {
            gload_lds16(arow + (kt + 1) * 64, &buf[cur ^ 1][0][wid << 10]);
            gload_lds16(bcol + (kt + 1) * 64, &buf[cur ^ 1][1][wid << 10]);
        }
        i64x2 bq[4];
#pragma unroll
        for (int n = 0; n < 4; ++n)
            bq[n] = *(const i64x2*)(Bb[cur] + (n << 10));
#pragma unroll
        for (int m = 0; m < 4; ++m) {
            const i64x2 aq = *(const i64x2*)(Ab[cur] + (m << 10));
#pragma unroll
            for (int n = 0; n < 4; ++n)
                acc[m][n] = __builtin_amdgcn_mfma_f32_16x16x32_fp8_fp8(aq[0], bq[n][0], acc[m][n], 0, 0, 0);
#pragma unroll
            for (int n = 0; n < 4; ++n)
                acc[m][n] = __builtin_amdgcn_mfma_f32_16x16x32_fp8_fp8(aq[1], bq[n][1], acc[m][n], 0, 0, 0);
        }
        __syncthreads();
    }

    // ---- epilogue: C/D layout col=lane&15, row=(lane>>4)*4+reg ----
    float* rsum4 = (float*)&buf[0][0][0];   // [256][4] per-(row,wc) slots
    float* csum4 = rsum4 + 1024;            // [256][4] per-(col,wr) slots
    float* lured = csum4 + 1024;            // [16]

    const int  rsub  = (lane >> 4) << 2;
    const int  csub  = lane & 15;
    const bool inreg = (ct < 8) || (rt >= 8 && ct < 16);  // lunif sub-blocks
    const int  rbase = row0 + (wr << 6);
    const int  cbase = col0 + (wc << 6);

    float lu = 0.0f;
    float cs[4] = {0.0f, 0.0f, 0.0f, 0.0f};
#pragma unroll
    for (int m = 0; m < 4; ++m) {
        float rs[4] = {0.0f, 0.0f, 0.0f, 0.0f};
#pragma unroll
        for (int n = 0; n < 4; ++n) {
            const int gcol = cbase + (n << 4) + csub;
#pragma unroll
            for (int r = 0; r < 4; ++r) {
                const int grow = rbase + (m << 4) + rsub + r;
                const float s = acc[m][n][r];
                float e = __expf(10.0f * s);
                if (isdiag) e = (grow != gcol) ? e : 0.0f;
                rs[r] += e;
                cs[n] += e;
                if (inreg && (!isdiag || gcol > grow)) {
                    const float d2 = fmaxf(2.0f - 2.0f * s, 0.0f);
                    lu += __expf(-2.0f * d2);
                }
            }
        }
#pragma unroll
        for (int off = 1; off < 16; off <<= 1) {
#pragma unroll
            for (int r = 0; r < 4; ++r) rs[r] += __shfl_xor(rs[r], off);
        }
        if ((lane & 15) == 0) {
#pragma unroll
            for (int r = 0; r < 4; ++r)
                rsum4[((wr << 6) + (m << 4) + rsub + r) * 4 + wc] = rs[r];
        }
    }
    if (!isdiag) {
#pragma unroll
        for (int off = 16; off < 64; off <<= 1) {
#pragma unroll
            for (int n = 0; n < 4; ++n) cs[n] += __shfl_xor(cs[n], off);
        }
        if (lane < 16) {
#pragma unroll
            for (int n = 0; n < 4; ++n)
                csum4[((wc << 6) + (n << 4) + lane) * 4 + wr] = cs[n];
        }
    }
#pragma unroll
    for (int off = 1; off < 64; off <<= 1) lu += __shfl_xor(lu, off);
    if (lane == 0) lured[wid] = lu;
    __syncthreads();

    if (t == 0) {
        float s = 0.0f;
#pragma unroll
        for (int w = 0; w < 16; ++w) s += lured[w];
        lup[rt * NT2 + ct] = s;
    }
    if (t < 256) {
        const float* p = rsum4 + t * 4;
        partials[(size_t)(row0 + t) * NT2 + ct] = ((p[0] + p[1]) + p[2]) + p[3];
    } else if (t < 512 && !isdiag) {
        const float* p = csum4 + (t - 256) * 4;
        partials[(size_t)(col0 + t - 256) * NT2 + rt] = ((p[0] + p[1]) + p[2]) + p[3];
    }
}

// --------- Kernel 3a: per-row denom -> log, 128 rows per block --------------
__global__ __launch_bounds__(128) void logred_kernel(
    const float* __restrict__ partials, double* __restrict__ red_log)
{
    const int t   = threadIdx.x;
    const int row = blockIdx.x * 128 + t;
    const float* p = partials + (size_t)row * NT2;
    float dsum = 0.0f;
#pragma unroll
    for (int i = 0; i < NT2; ++i) dsum += p[i];
    double l = log((double)dsum);
    __shared__ double sd[128];
    sd[t] = l;
    __syncthreads();
    for (int s = 64; s > 0; s >>= 1) {
        if (t < s) sd[t] += sd[t + s];
        __syncthreads();
    }
    if (t == 0) red_log[blockIdx.x] = sd[0];
}

// --------- Kernel 3b: final scalars --------------------------------------
__global__ __launch_bounds__(256) void final_kernel(
    const double* __restrict__ red_log, const float* __restrict__ pos,
    const float* __restrict__ lup, float* __restrict__ out)
{
    const int t = threadIdx.x;
    double dlog = 0.0, dpos = 0.0, ds1 = 0.0, ds2 = 0.0;
    if (t < 64) dlog = red_log[t];
    for (int i = t; i < NB; i += 256) dpos += (double)pos[i];
    for (int i = t; i < NT2 * NT2; i += 256) {
        const int rt = i >> 5, ct = i & 31;
        if (rt > ct) continue;                 // only upper-tri tiles written
        const double v = (double)lup[i];
        if (rt < 8 && ct < 8) ds1 += v;
        else if (rt >= 8 && rt < 16 && ct >= 8 && ct < 16) ds2 += v;
    }
    __shared__ double sd[4][256];
    sd[0][t] = dlog; sd[1][t] = dpos; sd[2][t] = ds1; sd[3][t] = ds2;
    __syncthreads();
    for (int s = 128; s > 0; s >>= 1) {
        if (t < s) {
            sd[0][t] += sd[0][t + s]; sd[1][t] += sd[1][t + s];
            sd[2][t] += sd[2][t + s]; sd[3][t] += sd[3][t + s];
        }
        __syncthreads();
    }
    if (t == 0) {
        const double mean_pos = sd[1][0] / (double)NB;
        const double loss   = sd[0][0] / (double)N2 - mean_pos * 10.0;   // /TEMP
        const double lalign = 2.0 - 2.0 * mean_pos;
        const double C      = 2048.0 * 2047.0 * 0.5;
        const double lunif  = 0.5 * (log(sd[2][0] / C) + log(sd[3][0] / C));
        out[0] = (float)loss;
        out[1] = (float)lalign;
        out[2] = (float)lunif;
    }
}

extern "C" void kernel_launch(void* const* d_in, const int* in_sizes, int n_in,
                              void* d_out, int out_size, void* d_ws, size_t ws_size,
                              hipStream_t stream) {
    const float* p1 = (const float*)d_in[0];
    const float* p2 = (const float*)d_in[1];
    float* out = (float*)d_out;

    char* ws = (char*)d_ws;
    unsigned char* zq = (unsigned char*)ws;                              // 8 MB
    float*  partials  = (float*)(ws + ((size_t)8 << 20));                // 1 MB [8192][32]
    float*  pos       = (float*)(ws + ((size_t)9 << 20));                // 16 KB
    float*  lup       = (float*)(ws + ((size_t)9 << 20) + 16384);        // 4 KB
    double* red_log   = (double*)(ws + ((size_t)9 << 20) + 16384 + 4096);// 512 B

    hipLaunchKernelGGL(norm_kernel,   dim3(NB),     dim3(256),  0, stream, p1, p2, zq, pos);
    hipLaunchKernelGGL(sim_kernel,    dim3(NTILES), dim3(1024), 0, stream, zq, partials, lup);
    hipLaunchKernelGGL(logred_kernel, dim3(64),     dim3(128),  0, stream, partials, red_log);
    hipLaunchKernelGGL(final_kernel,  dim3(1),      dim3(256),  0, stream, red_log, pos, lup, out);
}

// Round 10
// 102.851 us; speedup vs baseline: 6.7613x; 6.7613x over previous
//
#include <hip/hip_runtime.h>
#include <hip/hip_bf16.h>
#include <math.h>

#define DIM 1024
#define NB  4096      // B
#define N2  8192      // 2B
#define BT  256       // output tile dim
#define NT2 32        // N2 / BT
#define NTILES 528    // NT2*(NT2+1)/2 upper-triangular tiles

typedef float f32x4 __attribute__((ext_vector_type(4)));
typedef long  i64x2 __attribute__((ext_vector_type(2)));

__device__ __forceinline__ void gload_lds16(const unsigned char* g, unsigned char* l) {
    __builtin_amdgcn_global_load_lds((__attribute__((address_space(1))) void*)(g),
                                     (__attribute__((address_space(3))) void*)(l),
                                     16, 0, 0);
}

// fp8 e4m3fn encode, round-to-nearest-even (manual fallback)
__device__ __forceinline__ unsigned char to_fp8(float x) {
    unsigned int u = __float_as_uint(x);
    unsigned char s = (unsigned char)((u >> 24) & 0x80);
    int e = (int)((u >> 23) & 0xFF) - 127;
    unsigned int m = u & 0x7FFFFF;
    if (e >= -6) {
        if (e > 8) return s | 0x7E;
        unsigned int keep = m >> 20;
        unsigned int rest = m & 0xFFFFF;
        if (rest > 0x80000u || (rest == 0x80000u && (keep & 1))) keep++;
        unsigned int v = ((unsigned int)(e + 7) << 3) + keep;
        if (v >= 0x7F) v = 0x7E;
        return s | (unsigned char)v;
    }
    if (e < -10) return s;
    int drop = 14 - e;
    unsigned int sig = 0x800000u | m;
    unsigned int keep = sig >> drop;
    unsigned int rem  = sig & ((1u << drop) - 1u);
    unsigned int half = 1u << (drop - 1);
    if (rem > half || (rem == half && (keep & 1))) keep++;
    return s | (unsigned char)keep;
}

__device__ __forceinline__ unsigned int pk4_fp8(float a, float b, float c, float d) {
#if __has_builtin(__builtin_amdgcn_cvt_pk_fp8_f32)
    unsigned int q = 0;
    q = (unsigned int)__builtin_amdgcn_cvt_pk_fp8_f32(a, b, (int)q, false);
    q = (unsigned int)__builtin_amdgcn_cvt_pk_fp8_f32(c, d, (int)q, true);
    return q;
#else
    union { unsigned int u; unsigned char cc[4]; } q;
    q.cc[0] = to_fp8(a); q.cc[1] = to_fp8(b); q.cc[2] = to_fp8(c); q.cc[3] = to_fp8(d);
    return q.u;
#endif
}

// ---------------- Kernel 1: normalize rows, emit fp8 z (k-interleaved), pos --
// Column permutation within each 64-block: global col j -> stored byte
//   j<32: (j>>3)*16 + (j&7);  j>=32: ((j-32)>>3)*16 + 8 + ((j-32)&7)
// so one 16B granule g of a row holds k in {8g..8g+7} U {32+8g..32+8g+7}:
// ds_read_b128 yields BOTH K=32 MFMA slices. Same perm on A and B => cancels.
__global__ __launch_bounds__(256) void norm_kernel(
    const float* __restrict__ p1, const float* __restrict__ p2,
    unsigned char* __restrict__ zq, float* __restrict__ pos)
{
    const int r = blockIdx.x;
    const int t = threadIdx.x;
    const float4 x1 = ((const float4*)(p1 + (size_t)r * DIM))[t];
    const float4 x2 = ((const float4*)(p2 + (size_t)r * DIM))[t];
    float s1  = x1.x*x1.x + x1.y*x1.y + x1.z*x1.z + x1.w*x1.w;
    float s2  = x2.x*x2.x + x2.y*x2.y + x2.z*x2.z + x2.w*x2.w;
    float s12 = x1.x*x2.x + x1.y*x2.y + x1.z*x2.z + x1.w*x2.w;
#pragma unroll
    for (int off = 1; off < 64; off <<= 1) {
        s1  += __shfl_xor(s1,  off);
        s2  += __shfl_xor(s2,  off);
        s12 += __shfl_xor(s12, off);
    }
    __shared__ float ls[3][4];
    const int wid = t >> 6;
    if ((t & 63) == 0) { ls[0][wid] = s1; ls[1][wid] = s2; ls[2][wid] = s12; }
    __syncthreads();
    s1  = ls[0][0] + ls[0][1] + ls[0][2] + ls[0][3];
    s2  = ls[1][0] + ls[1][1] + ls[1][2] + ls[1][3];
    s12 = ls[2][0] + ls[2][1] + ls[2][2] + ls[2][3];
    const float rn1 = 1.0f / fmaxf(sqrtf(s1), 1e-12f);
    const float rn2 = 1.0f / fmaxf(sqrtf(s2), 1e-12f);
    if (t == 0) pos[r] = s12 * rn1 * rn2;

    const int j0 = (t << 2) & 63;       // col within 64-block
    const int kb = t >> 4;              // 64-block index
    const int pb = (j0 < 32) ? (((j0 >> 3) << 4) + (j0 & 7))
                             : ((((j0 - 32) >> 3) << 4) + 8 + ((j0 - 32) & 7));
    const size_t off8 = (size_t)kb * 64 + pb;
    *(unsigned int*)(zq + (size_t)r * DIM + off8) =
        pk4_fp8(x1.x * rn1, x1.y * rn1, x1.z * rn1, x1.w * rn1);
    *(unsigned int*)(zq + (size_t)(NB + r) * DIM + off8) =
        pk4_fp8(x2.x * rn2, x2.y * rn2, x2.z * rn2, x2.w * rn2);
}

// ------- Kernel 2: 256^2 fp8 symmetric z.z^T, 16 waves (4x4), 64x64/wave ----
// grid = 528 static (one tile per block, XCD-swizzled); LDS 64 KB and
// VGPR<=64 allow 2 blocks co-resident per CU, so one block's MFMA fills the
// other's barrier stalls and the HW scheduler backfills the 16-block tail.
// NOTE: launch_bounds min-waves stays 4 — asking for 8 drops the register
// budget to 32 VGPRs and spills acc to scratch (R9: 1.6 GB writes, 6x slower).
__global__ __launch_bounds__(1024, 4) void sim_kernel(
    const unsigned char* __restrict__ zq,
    float* __restrict__ partials,    // [N2][NT2]
    float* __restrict__ lup)         // [NT2*NT2], rt<=ct slots only
{
    __shared__ __align__(16) unsigned char buf[2][2][BT * 64]; // 64 KB
    const int t    = threadIdx.x;
    const int lane = t & 63;
    const int wid  = t >> 6;       // 0..15
    const int wr   = wid >> 2;     // 0..3 (64-row strip)
    const int wc   = wid & 3;      // 0..3 (64-col strip)

    const int bid = blockIdx.x;
    const int job = (bid & 7) * (NTILES / 8) + (bid >> 3);   // bijective XCD swizzle
    int rt = 0;
    while ((rt + 1) * NT2 - (((rt + 1) * rt) >> 1) <= job) ++rt;
    const int ct = rt + job - (rt * NT2 - ((rt * (rt - 1)) >> 1));
    const bool isdiag = (rt == ct);
    const int row0 = rt * BT;
    const int col0 = ct * BT;

    const int fr = lane & 15;      // fragment row (A) / col (B)
    const int kg = lane >> 4;      // k-group 0..3
    const int aoff = (((wr << 6) + fr) << 6) + (kg << 4);
    const int boff = (((wc << 6) + fr) << 6) + (kg << 4);
    const unsigned char* Ab[2] = { &buf[0][0][0] + aoff, &buf[1][0][0] + aoff };
    const unsigned char* Bb[2] = { &buf[0][1][0] + boff, &buf[1][1][0] + boff };

    // staging: wave w covers rows [16w,16w+16); lane: row 16w+(l>>2), granule l&3
    const int srow = (wid << 4) + (lane >> 2);
    const int sgr  = (lane & 3) << 4;
    const unsigned char* arow = zq + (size_t)(row0 + srow) * DIM + sgr;
    const unsigned char* bcol = zq + (size_t)(col0 + srow) * DIM + sgr;

    f32x4 acc[4][4] = {};

    // prologue: K-tile 0 -> buf0
    gload_lds16(arow, &buf[0][0][wid << 10]);
    gload_lds16(bcol, &buf[0][1][wid << 10]);
    __syncthreads();

#pragma unroll
    for (int kt = 0; kt < 16; ++kt) {
        const int cur = kt & 1;
        if (kt < 15) {
            gload_lds16(arow + (kt + 1) * 64, &buf[cur ^ 1][0][wid << 10]);
            gload_lds16(bcol + (kt + 1) * 64, &buf[cur ^ 1][1][wid << 10]);
        }
        i64x2 bq[4];
#pragma unroll
        for (int n = 0; n < 4; ++n)
            bq[n] = *(const i64x2*)(Bb[cur] + (n << 10));
#pragma unroll
        for (int m = 0; m < 4; ++m) {
            const i64x2 aq = *(const i64x2*)(Ab[cur] + (m << 10));
#pragma unroll
            for (int n = 0; n < 4; ++n)
                acc[m][n] = __builtin_amdgcn_mfma_f32_16x16x32_fp8_fp8(aq[0], bq[n][0], acc[m][n], 0, 0, 0);
#pragma unroll
            for (int n = 0; n < 4; ++n)
                acc[m][n] = __builtin_amdgcn_mfma_f32_16x16x32_fp8_fp8(aq[1], bq[n][1], acc[m][n], 0, 0, 0);
        }
        __syncthreads();
    }

    // ---- epilogue: C/D layout col=lane&15, row=(lane>>4)*4+reg ----
    float* rsum4 = (float*)&buf[0][0][0];   // [256][4] per-(row,wc) slots
    float* csum4 = rsum4 + 1024;            // [256][4] per-(col,wr) slots
    float* lured = csum4 + 1024;            // [16]

    const int  rsub  = (lane >> 4) << 2;
    const int  csub  = lane & 15;
    const bool inreg = (ct < 8) || (rt >= 8 && ct < 16);  // lunif sub-blocks
    const int  rbase = row0 + (wr << 6);
    const int  cbase = col0 + (wc << 6);

    float lu = 0.0f;
    float cs[4] = {0.0f, 0.0f, 0.0f, 0.0f};
#pragma unroll
    for (int m = 0; m < 4; ++m) {
        float rs[4] = {0.0f, 0.0f, 0.0f, 0.0f};
#pragma unroll
        for (int n = 0; n < 4; ++n) {
            const int gcol = cbase + (n << 4) + csub;
#pragma unroll
            for (int r = 0; r < 4; ++r) {
                const int grow = rbase + (m << 4) + rsub + r;
                const float s = acc[m][n][r];
                float e = __expf(10.0f * s);
                if (isdiag) e = (grow != gcol) ? e : 0.0f;
                rs[r] += e;
                cs[n] += e;
                if (inreg && (!isdiag || gcol > grow)) {
                    const float d2 = fmaxf(2.0f - 2.0f * s, 0.0f);
                    lu += __expf(-2.0f * d2);
                }
            }
        }
#pragma unroll
        for (int off = 1; off < 16; off <<= 1) {
#pragma unroll
            for (int r = 0; r < 4; ++r) rs[r] += __shfl_xor(rs[r], off);
        }
        if ((lane & 15) == 0) {
#pragma unroll
            for (int r = 0; r < 4; ++r)
                rsum4[((wr << 6) + (m << 4) + rsub + r) * 4 + wc] = rs[r];
        }
    }
    if (!isdiag) {
#pragma unroll
        for (int off = 16; off < 64; off <<= 1) {
#pragma unroll
            for (int n = 0; n < 4; ++n) cs[n] += __shfl_xor(cs[n], off);
        }
        if (lane < 16) {
#pragma unroll
            for (int n = 0; n < 4; ++n)
                csum4[((wc << 6) + (n << 4) + lane) * 4 + wr] = cs[n];
        }
    }
#pragma unroll
    for (int off = 1; off < 64; off <<= 1) lu += __shfl_xor(lu, off);
    if (lane == 0) lured[wid] = lu;
    __syncthreads();

    if (t == 0) {
        float s = 0.0f;
#pragma unroll
        for (int w = 0; w < 16; ++w) s += lured[w];
        lup[rt * NT2 + ct] = s;
    }
    if (t < 256) {
        const float* p = rsum4 + t * 4;
        partials[(size_t)(row0 + t) * NT2 + ct] = ((p[0] + p[1]) + p[2]) + p[3];
    } else if (t < 512 && !isdiag) {
        const float* p = csum4 + (t - 256) * 4;
        partials[(size_t)(col0 + t - 256) * NT2 + rt] = ((p[0] + p[1]) + p[2]) + p[3];
    }
}

// --------- Kernel 3a: per-row denom -> log, 128 rows per block --------------
__global__ __launch_bounds__(128) void logred_kernel(
    const float* __restrict__ partials, double* __restrict__ red_log)
{
    const int t   = threadIdx.x;
    const int row = blockIdx.x * 128 + t;
    const float* p = partials + (size_t)row * NT2;
    float dsum = 0.0f;
#pragma unroll
    for (int i = 0; i < NT2; ++i) dsum += p[i];
    double l = log((double)dsum);
    __shared__ double sd[128];
    sd[t] = l;
    __syncthreads();
    for (int s = 64; s > 0; s >>= 1) {
        if (t < s) sd[t] += sd[t + s];
        __syncthreads();
    }
    if (t == 0) red_log[blockIdx.x] = sd[0];
}

// --------- Kernel 3b: final scalars --------------------------------------
__global__ __launch_bounds__(256) void final_kernel(
    const double* __restrict__ red_log, const float* __restrict__ pos,
    const float* __restrict__ lup, float* __restrict__ out)
{
    const int t = threadIdx.x;
    double dlog = 0.0, dpos = 0.0, ds1 = 0.0, ds2 = 0.0;
    if (t < 64) dlog = red_log[t];
    for (int i = t; i < NB; i += 256) dpos += (double)pos[i];
    for (int i = t; i < NT2 * NT2; i += 256) {
        const int rt = i >> 5, ct = i & 31;
        if (rt > ct) continue;                 // only upper-tri tiles written
        const double v = (double)lup[i];
        if (rt < 8 && ct < 8) ds1 += v;
        else if (rt >= 8 && rt < 16 && ct >= 8 && ct < 16) ds2 += v;
    }
    __shared__ double sd[4][256];
    sd[0][t] = dlog; sd[1][t] = dpos; sd[2][t] = ds1; sd[3][t] = ds2;
    __syncthreads();
    for (int s = 128; s > 0; s >>= 1) {
        if (t < s) {
            sd[0][t] += sd[0][t + s]; sd[1][t] += sd[1][t + s];
            sd[2][t] += sd[2][t + s]; sd[3][t] += sd[3][t + s];
        }
        __syncthreads();
    }
    if (t == 0) {
        const double mean_pos = sd[1][0] / (double)NB;
        const double loss   = sd[0][0] / (double)N2 - mean_pos * 10.0;   // /TEMP
        const double lalign = 2.0 - 2.0 * mean_pos;
        const double C      = 2048.0 * 2047.0 * 0.5;
        const double lunif  = 0.5 * (log(sd[2][0] / C) + log(sd[3][0] / C));
        out[0] = (float)loss;
        out[1] = (float)lalign;
        out[2] = (float)lunif;
    }
}

extern "C" void kernel_launch(void* const* d_in, const int* in_sizes, int n_in,
                              void* d_out, int out_size, void* d_ws, size_t ws_size,
                              hipStream_t stream) {
    const float* p1 = (const float*)d_in[0];
    const float* p2 = (const float*)d_in[1];
    float* out = (float*)d_out;

    char* ws = (char*)d_ws;
    unsigned char* zq = (unsigned char*)ws;                              // 8 MB
    float*  partials  = (float*)(ws + ((size_t)8 << 20));                // 1 MB [8192][32]
    float*  pos       = (float*)(ws + ((size_t)9 << 20));                // 16 KB
    float*  lup       = (float*)(ws + ((size_t)9 << 20) + 16384);        // 4 KB
    double* red_log   = (double*)(ws + ((size_t)9 << 20) + 16384 + 4096);// 512 B

    hipLaunchKernelGGL(norm_kernel,   dim3(NB),     dim3(256),  0, stream, p1, p2, zq, pos);
    hipLaunchKernelGGL(sim_kernel,    dim3(NTILES), dim3(1024), 0, stream, zq, partials, lup);
    hipLaunchKernelGGL(logred_kernel, dim3(64),     dim3(128),  0, stream, partials, red_log);
    hipLaunchKernelGGL(final_kernel,  dim3(1),      dim3(256),  0, stream, red_log, pos, lup, out);
}